// Round 4
// baseline (204.639 us; speedup 1.0000x reference)
//
#include <hip/hip_runtime.h>
#include <hip/hip_fp16.h>

// Problem constants (match reference)
#define BB      2048
#define CC      1024
#define FF      128
#define NBLK    256
#define RPB     8        // rows per block (NBLK*RPB == BB)
#define TPB     512      // 8 waves
#define NITER   10
#define SUBR    8        // colsum accumulator spreading (256/8 = 32-way)
#define SCALING_F (2048.0f / 100000.0f)

// Static device storage: no hipMalloc, safe under graph capture, never
// poisoned by the harness (fully rewritten every call).
__device__ __align__(16) __half g_Kh[BB * CC];   // 4 MB fp16 K, L2-resident
__device__ float g_meanPart[NBLK];               // per-block D partial sums
__device__ float g_colsum[NITER * SUBR * CC];    // spread K^T u accumulators

// ---- K0: zero colsum + per-block partial sums of D -------------------------
__global__ void __launch_bounds__(TPB)
k0_prep(const float* __restrict__ D) {
    const int bid = blockIdx.x, tid = threadIdx.x;
    for (int i = bid * TPB + tid; i < NITER * SUBR * CC; i += NBLK * TPB)
        g_colsum[i] = 0.0f;
    const float4* D4 = (const float4*)D;
    float p = 0.0f;
    for (int i = bid * TPB + tid; i < BB * CC / 4; i += NBLK * TPB) {
        float4 d = D4[i];
        p += d.x + d.y + d.z + d.w;
    }
    #pragma unroll
    for (int off = 32; off > 0; off >>= 1) p += __shfl_down(p, off, 64);
    __shared__ float red[TPB / 64];
    if ((tid & 63) == 0) red[tid >> 6] = p;
    __syncthreads();
    if (tid == 0) {
        float s = 0.0f;
        #pragma unroll
        for (int k = 0; k < TPB / 64; ++k) s += red[k];
        g_meanPart[bid] = s;
    }
}

// ---- K1: dot GEMM + exp -> store K (fp16) to global -------------------------
__global__ void __launch_bounds__(TPB)
k1_buildK(const int* __restrict__ users, const int* __restrict__ items,
          const float* __restrict__ D, const float* __restrict__ iemb,
          const float* __restrict__ uemb) {
    const int bid = blockIdx.x, tid = threadIdx.x;
    const int r0 = bid * RPB;

    __shared__ float  uesh[RPB][FF];   // 4 KB
    __shared__ __half dott[RPB][CC];   // 16 KB
    __shared__ float  s2sh;

    if (tid < 256) {                   // stage 8 user embeddings (8x32 float4)
        int r = tid >> 5, f4 = tid & 31;
        int u = users[r0 + r];
        ((float4*)uesh[r])[f4] = ((const float4*)(uemb + (size_t)u * FF))[f4];
    }
    if (tid < 64) {                    // s2 = 5*B*C / sum(D)
        float s = g_meanPart[tid] + g_meanPart[tid + 64] +
                  g_meanPart[tid + 128] + g_meanPart[tid + 192];
        #pragma unroll
        for (int off = 32; off > 0; off >>= 1) s += __shfl_down(s, off, 64);
        if (tid == 0) s2sh = 5.0f * (float)(BB * CC) / s;
    }
    __syncthreads();

    // GEMM: ue reads are wave-uniform -> LDS broadcast (bandwidth-free)
    const float4* us = (const float4*)uesh;
    #pragma unroll
    for (int jj = 0; jj < CC / TPB; ++jj) {
        int j = jj * TPB + tid;
        float acc[RPB] = {};
        const float4* ip = (const float4*)(iemb + (size_t)j * FF);
        for (int f4 = 0; f4 < FF / 4; ++f4) {
            float4 a = ip[f4];
            #pragma unroll
            for (int r = 0; r < RPB; ++r) {
                float4 b = us[r * (FF / 4) + f4];
                acc[r] += a.x * b.x + a.y * b.y + a.z * b.z + a.w * b.w;
            }
        }
        #pragma unroll
        for (int r = 0; r < RPB; ++r) dott[r][j] = __float2half(acc[r]);
    }
    __syncthreads();

    const float s2 = s2sh;
    const int4*   it4 = (const int4*)(items + ((size_t)r0 << 10));
    const float4* D4  = (const float4*)(D + ((size_t)r0 << 10));
    uint2* K2 = (uint2*)(g_Kh + ((size_t)r0 << 10));   // 4 halves per elem
    for (int i = tid; i < RPB * CC / 4; i += TPB) {
        int4 iv = it4[i];
        float4 d = D4[i];
        int r = i >> 8;
        float4 kv;
        kv.x = __expf(5.0f * __half2float(dott[r][iv.x]) - s2 * d.x);
        kv.y = __expf(5.0f * __half2float(dott[r][iv.y]) - s2 * d.y);
        kv.z = __expf(5.0f * __half2float(dott[r][iv.z]) - s2 * d.z);
        kv.w = __expf(5.0f * __half2float(dott[r][iv.w]) - s2 * d.w);
        __half2 lo = __floats2half2_rn(kv.x, kv.y);
        __half2 hi = __floats2half2_rn(kv.z, kv.w);
        uint2 o;
        o.x = *reinterpret_cast<unsigned*>(&lo);
        o.y = *reinterpret_cast<unsigned*>(&hi);
        K2[i] = o;
    }
}

// ---- K_iter(t): v_t -> u = 1/(K v_t) -> colsum[t] += K^T u ------------------
// K read straight from L2 twice (row-striped, then col-striped); no LDS stage.
__global__ void __launch_bounds__(TPB)
k_iter(const float* __restrict__ caps, int t) {
    const int bid = blockIdx.x, tid = threadIdx.x;
    const int r0 = bid * RPB;

    __shared__ float vsh[CC];
    __shared__ float ush[RPB];

    // v_t (redundant per block); v_0 = 1
    for (int c = tid; c < CC; c += TPB) {
        float v = 1.0f;
        if (t > 0) {
            const float* base = g_colsum + (size_t)(t - 1) * SUBR * CC;
            float s = 0.0f;
            #pragma unroll
            for (int k = 0; k < SUBR; ++k) s += base[k * CC + c];
            v = caps[c] * SCALING_F / s;
        }
        vsh[c] = v;
    }
    __syncthreads();

    // u_w = 1/(K v)_w : one wave per row, coalesced half2 loads from L2
    {
        int w = tid >> 6, l = tid & 63;
        const __half2* kr = (const __half2*)(g_Kh + ((size_t)(r0 + w) << 10));
        const float2*  v2 = (const float2*)vsh;
        float p = 0.0f;
        #pragma unroll
        for (int i = 0; i < 8; ++i) {
            float2 k = __half22float2(kr[l + 64 * i]);
            float2 v = v2[l + 64 * i];
            p += k.x * v.x + k.y * v.y;
        }
        #pragma unroll
        for (int off = 32; off > 0; off >>= 1) p += __shfl_xor(p, off, 64);
        if (l == 0) ush[w] = 1.0f / p;
    }
    __syncthreads();

    // colsum: thread owns col pair 2*tid, loops the 8 rows (coalesced half2)
    {
        float sx = 0.0f, sy = 0.0f;
        #pragma unroll
        for (int r = 0; r < RPB; ++r) {
            const __half2* kp =
                (const __half2*)(g_Kh + ((size_t)(r0 + r) << 10)) + tid;
            float2 k = __half22float2(*kp);
            float ur = ush[r];            // broadcast LDS read
            sx += k.x * ur; sy += k.y * ur;
        }
        float* cb = g_colsum + ((size_t)t * SUBR + (bid & (SUBR - 1))) * CC
                  + 2 * tid;
        atomicAdd(cb, sx);
        atomicAdd(cb + 1, sy);
    }
}

// ---- K_final: v9 -> u10 -> v10 -> P = K * u (x) v ---------------------------
__global__ void __launch_bounds__(TPB)
k_final(const float* __restrict__ caps, float* __restrict__ out) {
    const int bid = blockIdx.x, tid = threadIdx.x;
    const int r0 = bid * RPB;

    __shared__ float vsh[CC];
    __shared__ float ush[RPB];

    // v9 from colsum[8]
    for (int c = tid; c < CC; c += TPB) {
        const float* base = g_colsum + (size_t)(NITER - 2) * SUBR * CC;
        float s = 0.0f;
        #pragma unroll
        for (int k = 0; k < SUBR; ++k) s += base[k * CC + c];
        vsh[c] = caps[c] * SCALING_F / s;
    }
    __syncthreads();

    // u10 = 1/(K v9)
    {
        int w = tid >> 6, l = tid & 63;
        const __half2* kr = (const __half2*)(g_Kh + ((size_t)(r0 + w) << 10));
        const float2*  v2 = (const float2*)vsh;
        float p = 0.0f;
        #pragma unroll
        for (int i = 0; i < 8; ++i) {
            float2 k = __half22float2(kr[l + 64 * i]);
            float2 v = v2[l + 64 * i];
            p += k.x * v.x + k.y * v.y;
        }
        #pragma unroll
        for (int off = 32; off > 0; off >>= 1) p += __shfl_xor(p, off, 64);
        if (l == 0) ush[w] = 1.0f / p;
    }
    __syncthreads();

    // v10 from colsum[9], overwrite vsh
    for (int c = tid; c < CC; c += TPB) {
        const float* base = g_colsum + (size_t)(NITER - 1) * SUBR * CC;
        float s = 0.0f;
        #pragma unroll
        for (int k = 0; k < SUBR; ++k) s += base[k * CC + c];
        vsh[c] = caps[c] * SCALING_F / s;
    }
    __syncthreads();

    // P: thread owns col pair 2*tid across the 8 rows; float2 stores
    {
        float2 v = *(const float2*)&vsh[2 * tid];
        #pragma unroll
        for (int r = 0; r < RPB; ++r) {
            const __half2* kp =
                (const __half2*)(g_Kh + ((size_t)(r0 + r) << 10)) + tid;
            float2 k = __half22float2(*kp);
            float ur = ush[r];
            float2 p; p.x = k.x * ur * v.x; p.y = k.y * ur * v.y;
            ((float2*)(out + ((size_t)(r0 + r) << 10)))[tid] = p;
        }
    }
}

extern "C" void kernel_launch(void* const* d_in, const int* in_sizes, int n_in,
                              void* d_out, int out_size, void* d_ws, size_t ws_size,
                              hipStream_t stream) {
    const int*   users = (const int*)d_in[0];
    const int*   items = (const int*)d_in[1];
    const float* D     = (const float*)d_in[2];
    const float* caps  = (const float*)d_in[3];
    const float* iemb  = (const float*)d_in[4];
    const float* uemb  = (const float*)d_in[5];
    float* out = (float*)d_out;

    hipLaunchKernelGGL(k0_prep,   dim3(NBLK), dim3(TPB), 0, stream, D);
    hipLaunchKernelGGL(k1_buildK, dim3(NBLK), dim3(TPB), 0, stream,
                       users, items, D, iemb, uemb);
    for (int t = 0; t < NITER; ++t)
        hipLaunchKernelGGL(k_iter, dim3(NBLK), dim3(TPB), 0, stream, caps, t);
    hipLaunchKernelGGL(k_final,  dim3(NBLK), dim3(TPB), 0, stream, caps, out);
}

// Round 5
// 193.065 us; speedup vs baseline: 1.0599x; 1.0599x over previous
//
#include <hip/hip_runtime.h>
#include <hip/hip_fp16.h>

// Problem constants (match reference)
#define BB      2048
#define CC      1024
#define FF      128
#define NBLK    256
#define RPB     8        // rows per block (NBLK*RPB == BB); also waves per block
#define TPB     512      // 8 waves: wave w owns row r0+w in iter kernels
#define NITER   10
#define SUBR    8        // colsum accumulator spreading (256/8 = 32-way)
#define SCALING_F (2048.0f / 100000.0f)

// Static device storage: no hipMalloc, safe under graph capture, never
// poisoned by the harness (fully rewritten every call).
__device__ __align__(16) float g_K[BB * CC];   // 8 MB fp32 K, L2-resident
__device__ float g_meanPart[NBLK];             // per-block D partial sums
__device__ float g_colsum[NITER * SUBR * CC];  // spread K^T u accumulators

// ---- K0: zero colsum + per-block partial sums of D -------------------------
__global__ void __launch_bounds__(TPB)
k0_prep(const float* __restrict__ D) {
    const int bid = blockIdx.x, tid = threadIdx.x;
    for (int i = bid * TPB + tid; i < NITER * SUBR * CC; i += NBLK * TPB)
        g_colsum[i] = 0.0f;
    const float4* D4 = (const float4*)D;
    float p = 0.0f;
    for (int i = bid * TPB + tid; i < BB * CC / 4; i += NBLK * TPB) {
        float4 d = D4[i];
        p += d.x + d.y + d.z + d.w;
    }
    #pragma unroll
    for (int off = 32; off > 0; off >>= 1) p += __shfl_down(p, off, 64);
    __shared__ float red[TPB / 64];
    if ((tid & 63) == 0) red[tid >> 6] = p;
    __syncthreads();
    if (tid == 0) {
        float s = 0.0f;
        #pragma unroll
        for (int k = 0; k < TPB / 64; ++k) s += red[k];
        g_meanPart[bid] = s;
    }
}

// ---- K1: dot GEMM + exp -> store K (fp32) to global -------------------------
__global__ void __launch_bounds__(TPB)
k1_buildK(const int* __restrict__ users, const int* __restrict__ items,
          const float* __restrict__ D, const float* __restrict__ iemb,
          const float* __restrict__ uemb) {
    const int bid = blockIdx.x, tid = threadIdx.x;
    const int r0 = bid * RPB;

    __shared__ float  uesh[RPB][FF];   // 4 KB
    __shared__ __half dott[RPB][CC];   // 16 KB
    __shared__ float  s2sh;

    if (tid < 256) {                   // stage 8 user embeddings (8x32 float4)
        int r = tid >> 5, f4 = tid & 31;
        int u = users[r0 + r];
        ((float4*)uesh[r])[f4] = ((const float4*)(uemb + (size_t)u * FF))[f4];
    }
    if (tid < 64) {                    // s2 = 5*B*C / sum(D)
        float s = g_meanPart[tid] + g_meanPart[tid + 64] +
                  g_meanPart[tid + 128] + g_meanPart[tid + 192];
        #pragma unroll
        for (int off = 32; off > 0; off >>= 1) s += __shfl_down(s, off, 64);
        if (tid == 0) s2sh = 5.0f * (float)(BB * CC) / s;
    }
    __syncthreads();

    // GEMM: ue reads are wave-uniform -> LDS broadcast (bandwidth-free)
    const float4* us = (const float4*)uesh;
    #pragma unroll
    for (int jj = 0; jj < CC / TPB; ++jj) {
        int j = jj * TPB + tid;
        float acc[RPB] = {};
        const float4* ip = (const float4*)(iemb + (size_t)j * FF);
        for (int f4 = 0; f4 < FF / 4; ++f4) {
            float4 a = ip[f4];
            #pragma unroll
            for (int r = 0; r < RPB; ++r) {
                float4 b = us[r * (FF / 4) + f4];
                acc[r] += a.x * b.x + a.y * b.y + a.z * b.z + a.w * b.w;
            }
        }
        #pragma unroll
        for (int r = 0; r < RPB; ++r) dott[r][j] = __float2half(acc[r]);
    }
    __syncthreads();

    const float s2 = s2sh;
    const int4*   it4 = (const int4*)(items + ((size_t)r0 << 10));
    const float4* D4  = (const float4*)(D + ((size_t)r0 << 10));
    float4*       K4  = (float4*)(g_K + ((size_t)r0 << 10));
    for (int i = tid; i < RPB * CC / 4; i += TPB) {
        int4 iv = it4[i];
        float4 d = D4[i];
        int r = i >> 8;
        float4 kv;
        kv.x = __expf(5.0f * __half2float(dott[r][iv.x]) - s2 * d.x);
        kv.y = __expf(5.0f * __half2float(dott[r][iv.y]) - s2 * d.y);
        kv.z = __expf(5.0f * __half2float(dott[r][iv.z]) - s2 * d.z);
        kv.w = __expf(5.0f * __half2float(dott[r][iv.w]) - s2 * d.w);
        K4[i] = kv;
    }
}

// ---- K_iter(t): v_t -> u = 1/(K v_t) -> colsum[t] += K^T u ------------------
// Wave w owns row r0+w: K row loaded ONCE into registers (issued before the
// v-phase so global latency overlaps it), Kv from regs, LDS copy written for
// the colsum phase. One LDS read pass + 2 barriers total.
__global__ void __launch_bounds__(TPB)
k_iter(const float* __restrict__ caps, int t) {
    const int bid = blockIdx.x, tid = threadIdx.x;
    const int r0 = bid * RPB;
    const int w = tid >> 6, l = tid & 63;

    __shared__ float Kt[RPB][CC];      // 32 KB
    __shared__ float vsh[CC];
    __shared__ float ush[RPB];

    // Issue this wave's K row (16 floats/lane, 4 independent float4 loads)
    const float4* kr = (const float4*)(g_K + ((size_t)(r0 + w) << 10));
    float4 k4[4];
    #pragma unroll
    for (int j = 0; j < 4; ++j) k4[j] = kr[l + 64 * j];

    // v_t while loads are in flight (redundant per block); v_0 = 1
    for (int c = tid; c < CC; c += TPB) {
        float v = 1.0f;
        if (t > 0) {
            const float* base = g_colsum + (size_t)(t - 1) * SUBR * CC;
            float s = 0.0f;
            #pragma unroll
            for (int k = 0; k < SUBR; ++k) s += base[k * CC + c];
            v = caps[c] * SCALING_F / s;
        }
        vsh[c] = v;
    }
    __syncthreads();

    // u_w = 1/(K v)_w from registers; stash K row into LDS for colsum phase
    {
        const float4* v4 = (const float4*)vsh;
        float4* KtF4 = (float4*)Kt[w];
        float p = 0.0f;
        #pragma unroll
        for (int j = 0; j < 4; ++j) {
            float4 v = v4[l + 64 * j];
            p += k4[j].x * v.x + k4[j].y * v.y + k4[j].z * v.z + k4[j].w * v.w;
            KtF4[l + 64 * j] = k4[j];
        }
        #pragma unroll
        for (int off = 32; off > 0; off >>= 1) p += __shfl_xor(p, off, 64);
        if (l == 0) ush[w] = 1.0f / p;
    }
    __syncthreads();

    // colsum: thread owns col pair 2*tid across the 8 rows (LDS reads)
    {
        float sx = 0.0f, sy = 0.0f;
        #pragma unroll
        for (int r = 0; r < RPB; ++r) {
            float2 k = *(const float2*)&Kt[r][2 * tid];
            float ur = ush[r];
            sx += k.x * ur; sy += k.y * ur;
        }
        float* cb = g_colsum + ((size_t)t * SUBR + (bid & (SUBR - 1))) * CC
                  + 2 * tid;
        atomicAdd(cb, sx);
        atomicAdd(cb + 1, sy);
    }
}

// ---- K_final: v9 -> u10 -> v10 -> P = K * u (x) v ---------------------------
// K read exactly once (registers); P stored straight from registers.
__global__ void __launch_bounds__(TPB)
k_final(const float* __restrict__ caps, float* __restrict__ out) {
    const int bid = blockIdx.x, tid = threadIdx.x;
    const int r0 = bid * RPB;
    const int w = tid >> 6, l = tid & 63;

    __shared__ float vsh[CC];

    // Issue this wave's K row
    const float4* kr = (const float4*)(g_K + ((size_t)(r0 + w) << 10));
    float4 k4[4];
    #pragma unroll
    for (int j = 0; j < 4; ++j) k4[j] = kr[l + 64 * j];

    // v9 from colsum[8] (overlaps K loads)
    for (int c = tid; c < CC; c += TPB) {
        const float* base = g_colsum + (size_t)(NITER - 2) * SUBR * CC;
        float s = 0.0f;
        #pragma unroll
        for (int k = 0; k < SUBR; ++k) s += base[k * CC + c];
        vsh[c] = caps[c] * SCALING_F / s;
    }
    __syncthreads();

    // u10 = 1/(K v9): xor-reduce leaves the value in every lane
    float u;
    {
        const float4* v4 = (const float4*)vsh;
        float p = 0.0f;
        #pragma unroll
        for (int j = 0; j < 4; ++j) {
            float4 v = v4[l + 64 * j];
            p += k4[j].x * v.x + k4[j].y * v.y + k4[j].z * v.z + k4[j].w * v.w;
        }
        #pragma unroll
        for (int off = 32; off > 0; off >>= 1) p += __shfl_xor(p, off, 64);
        u = 1.0f / p;
    }
    __syncthreads();

    // v10 from colsum[9], overwrite vsh
    for (int c = tid; c < CC; c += TPB) {
        const float* base = g_colsum + (size_t)(NITER - 1) * SUBR * CC;
        float s = 0.0f;
        #pragma unroll
        for (int k = 0; k < SUBR; ++k) s += base[k * CC + c];
        vsh[c] = caps[c] * SCALING_F / s;
    }
    __syncthreads();

    // P[w][*] straight from registers: coalesced 1 KB/wave float4 stores
    {
        const float4* v4 = (const float4*)vsh;
        float4* o4 = (float4*)(out + ((size_t)(r0 + w) << 10));
        #pragma unroll
        for (int j = 0; j < 4; ++j) {
            float4 v = v4[l + 64 * j];
            float4 p;
            p.x = k4[j].x * u * v.x;  p.y = k4[j].y * u * v.y;
            p.z = k4[j].z * u * v.z;  p.w = k4[j].w * u * v.w;
            o4[l + 64 * j] = p;
        }
    }
}

extern "C" void kernel_launch(void* const* d_in, const int* in_sizes, int n_in,
                              void* d_out, int out_size, void* d_ws, size_t ws_size,
                              hipStream_t stream) {
    const int*   users = (const int*)d_in[0];
    const int*   items = (const int*)d_in[1];
    const float* D     = (const float*)d_in[2];
    const float* caps  = (const float*)d_in[3];
    const float* iemb  = (const float*)d_in[4];
    const float* uemb  = (const float*)d_in[5];
    float* out = (float*)d_out;

    hipLaunchKernelGGL(k0_prep,   dim3(NBLK), dim3(TPB), 0, stream, D);
    hipLaunchKernelGGL(k1_buildK, dim3(NBLK), dim3(TPB), 0, stream,
                       users, items, D, iemb, uemb);
    for (int t = 0; t < NITER; ++t)
        hipLaunchKernelGGL(k_iter, dim3(NBLK), dim3(TPB), 0, stream, caps, t);
    hipLaunchKernelGGL(k_final,  dim3(NBLK), dim3(TPB), 0, stream, caps, out);
}